// Round 5
// baseline (145.436 us; speedup 1.0000x reference)
//
#include <hip/hip_runtime.h>
#include <stdint.h>

// ---------- types ----------
typedef __attribute__((ext_vector_type(8))) __bf16 fragAB;  // 8 bf16 = 4 VGPR
typedef __attribute__((ext_vector_type(4))) float f32x4;

__device__ __forceinline__ unsigned short f2bf(float f) {
    union { float f; unsigned int u; } v; v.f = f;
    unsigned int u = v.u + 0x7fffu + ((v.u >> 16) & 1u);   // RNE
    return (unsigned short)(u >> 16);
}

__device__ __forceinline__ f32x4 MFMA(fragAB a, fragAB b, f32x4 c) {
    return __builtin_amdgcn_mfma_f32_16x16x32_bf16(a, b, c, 0, 0, 0);
}

// async global->LDS, 16B per lane; LDS dest = wave-uniform base + lane*16
__device__ __forceinline__ void gl16(const void* g, void* l) {
    __builtin_amdgcn_global_load_lds((const __attribute__((address_space(1))) void*)g,
                                     (__attribute__((address_space(3))) void*)l, 16, 0, 0);
}

__device__ __forceinline__ float fsin_rev(float rev) {   // sin(2*pi*rev)
    float r; asm("v_sin_f32 %0, %1" : "=v"(r) : "v"(rev)); return r;
}
__device__ __forceinline__ unsigned int cvtpk(float lo, float hi) {  // 2xbf16 RNE
    unsigned int r; asm("v_cvt_pk_bf16_f32 %0, %1, %2" : "=v"(r) : "v"(lo), "v"(hi)); return r;
}

// ---------- fused fp32 -> bf16 convert (x + 4 weights in one launch) ----------
__global__ __launch_bounds__(256) void cvt_all(
    const float* __restrict__ x,  const float* __restrict__ wq, const float* __restrict__ wk,
    const float* __restrict__ wv, const float* __restrict__ wo,
    unsigned short* __restrict__ xb,  unsigned short* __restrict__ wqb, unsigned short* __restrict__ wkb,
    unsigned short* __restrict__ wvb, unsigned short* __restrict__ wob)
{
    const int bid = blockIdx.x;
    const float* s; unsigned short* d; int off;
    if (bid < 4096)      { s = x;  d = xb;  off = bid; }
    else if (bid < 5120) { s = wq; d = wqb; off = bid - 4096; }
    else if (bid < 6144) { s = wk; d = wkb; off = bid - 5120; }
    else if (bid < 7168) { s = wv; d = wvb; off = bid - 6144; }
    else                 { s = wo; d = wob; off = bid - 7168; }
    const int i = (off * 256 + threadIdx.x) * 4;
    float4 f = *(const float4*)(s + i);
    ushort4 o;
    o.x = f2bf(f.x); o.y = f2bf(f.y); o.z = f2bf(f.z); o.w = f2bf(f.w);
    *(ushort4*)(d + i) = o;
}

// ---------- GEMM (m97 structure, 128x128): Q/K/V projections ----------
__global__ __launch_bounds__(256, 2)
void gemm_k(const unsigned short* __restrict__ A,
            const unsigned short* __restrict__ W0, const unsigned short* __restrict__ W1,
            const unsigned short* __restrict__ W2,
            const float* __restrict__ b0, const float* __restrict__ b1, const float* __restrict__ b2,
            void* o0, void* o1, void* o2)
{
    __shared__ unsigned short As[8192];   // [128][64] linear, 16KB
    __shared__ unsigned short Ws[8192];

    const int z = blockIdx.z;
    const unsigned short* W = z == 0 ? W0 : (z == 1 ? W1 : W2);
    const float* bias        = z == 0 ? b0 : (z == 1 ? b1 : b2);
    void* out                = z == 0 ? o0 : (z == 1 ? o1 : o2);
    const int mode           = z == 2 ? 1 : 0;   // V -> transposed epilogue

    const int t = threadIdx.x;
    const int lane = t & 63;
    const int g = lane >> 4;
    const int c = lane & 15;
    const int w = t >> 6;
    const int wm = (w >> 1) * 64;
    const int wn = (w & 1) * 64;
    const int m0 = blockIdx.y * 128;
    const int n0 = blockIdx.x * 128;

    const int srow = lane >> 3;
    const int scol = (lane & 7) * 8;

    const f32x4 zz = {0.f, 0.f, 0.f, 0.f};
    f32x4 acc[4][4];
#pragma unroll
    for (int mi = 0; mi < 4; ++mi)
#pragma unroll
        for (int ni = 0; ni < 4; ++ni) acc[mi][ni] = zz;

    for (int kt = 0; kt < 16; ++kt) {
        const int k0 = kt * 64;
#pragma unroll
        for (int r = 0; r < 4; ++r) {
            gl16(A + (size_t)(m0 + 32 * w + 8 * r + srow) * 1024 + k0 + scol,
                 (unsigned short*)As + (w * 4 + r) * 512);
            gl16(W + (size_t)(n0 + 32 * w + 8 * r + srow) * 1024 + k0 + scol,
                 (unsigned short*)Ws + (w * 4 + r) * 512);
        }
        __syncthreads();
#pragma unroll
        for (int kk = 0; kk < 2; ++kk) {
            fragAB af[4], bfr[4];
#pragma unroll
            for (int mi = 0; mi < 4; ++mi)
                af[mi] = *(const fragAB*)((char*)As + (wm + mi * 16 + c) * 128 + kk * 64 + g * 16);
#pragma unroll
            for (int ni = 0; ni < 4; ++ni)
                bfr[ni] = *(const fragAB*)((char*)Ws + (wn + ni * 16 + c) * 128 + kk * 64 + g * 16);
#pragma unroll
            for (int mi = 0; mi < 4; ++mi)
#pragma unroll
                for (int ni = 0; ni < 4; ++ni)
                    acc[mi][ni] = MFMA(af[mi], bfr[ni], acc[mi][ni]);
        }
        __syncthreads();
    }

    float bv[4];
#pragma unroll
    for (int ni = 0; ni < 4; ++ni) bv[ni] = bias[n0 + wn + ni * 16 + c];

    if (mode == 0) {
        unsigned short* C = (unsigned short*)out;
#pragma unroll
        for (int mi = 0; mi < 4; ++mi)
#pragma unroll
            for (int ni = 0; ni < 4; ++ni)
#pragma unroll
                for (int j = 0; j < 4; ++j) {
                    const int grow = m0 + wm + mi * 16 + g * 4 + j;
                    const int gcol = n0 + wn + ni * 16 + c;
                    C[(size_t)grow * 1024 + gcol] = f2bf(acc[mi][ni][j] + bv[ni]);
                }
    } else {
        unsigned short* Vt = (unsigned short*)out;   // Vt[b][n][s]
#pragma unroll
        for (int mi = 0; mi < 4; ++mi)
#pragma unroll
            for (int ni = 0; ni < 4; ++ni) {
                const int gcol = n0 + wn + ni * 16 + c;
                const int mrow = m0 + wm + mi * 16 + g * 4;
                const int bb = mrow >> 11;
                const int s = mrow & 2047;
                ushort4 pk;
                pk.x = f2bf(acc[mi][ni][0] + bv[ni]);
                pk.y = f2bf(acc[mi][ni][1] + bv[ni]);
                pk.z = f2bf(acc[mi][ni][2] + bv[ni]);
                pk.w = f2bf(acc[mi][ni][3] + bv[ni]);
                *(ushort4*)(Vt + ((size_t)bb * 1024 + gcol) * 2048 + s) = pk;
            }
    }
}

// ---------- GEMM 64x128 tile, fp32 out: final projection ----------
__global__ __launch_bounds__(256, 4)
void gemm64(const unsigned short* __restrict__ A,
            const unsigned short* __restrict__ W,
            const float* __restrict__ bias, float* __restrict__ out)
{
    __shared__ unsigned short As[4096];   // [64][64]  8KB
    __shared__ unsigned short Ws[8192];   // [128][64] 16KB

    const int t = threadIdx.x;
    const int lane = t & 63;
    const int g = lane >> 4;
    const int c = lane & 15;
    const int w = t >> 6;
    const int wm = (w >> 1) * 32;
    const int wn = (w & 1) * 64;
    const int m0 = blockIdx.y * 64;
    const int n0 = blockIdx.x * 128;

    const int srow = lane >> 3;
    const int scol = (lane & 7) * 8;

    const f32x4 zz = {0.f, 0.f, 0.f, 0.f};
    f32x4 acc[2][4];
#pragma unroll
    for (int mi = 0; mi < 2; ++mi)
#pragma unroll
        for (int ni = 0; ni < 4; ++ni) acc[mi][ni] = zz;

    for (int kt = 0; kt < 16; ++kt) {
        const int k0 = kt * 64;
        gl16(A + (size_t)(m0 + 16 * w + srow) * 1024 + k0 + scol,
             (unsigned short*)As + (2 * w) * 512);
        gl16(A + (size_t)(m0 + 16 * w + 8 + srow) * 1024 + k0 + scol,
             (unsigned short*)As + (2 * w + 1) * 512);
#pragma unroll
        for (int r = 0; r < 4; ++r)
            gl16(W + (size_t)(n0 + 32 * w + 8 * r + srow) * 1024 + k0 + scol,
                 (unsigned short*)Ws + (w * 4 + r) * 512);
        __syncthreads();
#pragma unroll
        for (int kk = 0; kk < 2; ++kk) {
            fragAB af[2], bfr[4];
#pragma unroll
            for (int mi = 0; mi < 2; ++mi)
                af[mi] = *(const fragAB*)((char*)As + (wm + mi * 16 + c) * 128 + kk * 64 + g * 16);
#pragma unroll
            for (int ni = 0; ni < 4; ++ni)
                bfr[ni] = *(const fragAB*)((char*)Ws + (wn + ni * 16 + c) * 128 + kk * 64 + g * 16);
#pragma unroll
            for (int mi = 0; mi < 2; ++mi)
#pragma unroll
                for (int ni = 0; ni < 4; ++ni)
                    acc[mi][ni] = MFMA(af[mi], bfr[ni], acc[mi][ni]);
        }
        __syncthreads();
    }

#pragma unroll
    for (int ni = 0; ni < 4; ++ni) {
        const float bv = bias[n0 + wn + ni * 16 + c];
#pragma unroll
        for (int mi = 0; mi < 2; ++mi)
#pragma unroll
            for (int j = 0; j < 4; ++j) {
                const int grow = m0 + wm + mi * 16 + g * 4 + j;
                const int gcol = n0 + wn + ni * 16 + c;
                out[(size_t)grow * 1024 + gcol] = acc[mi][ni][j] + bv;
            }
    }
}

// ---------- fused sine attention v2: K/V direct global->reg, LDS = P only ----------
// QBLK=128, KVBLK=64, 4 waves, grid 512 XCD-chunked, 16KB LDS, ~190 VGPR (2 blk/CU).
// Per iter: issue K(kb+1)->regs, V(kb)->regs; QK(kb) from kf regs; sin->P LDS;
// lgkm-barrier; PV(kb) from P LDS + vf regs; barrier. No vmcnt drains anywhere.
#define SWZ(byteoff, row) ((byteoff) ^ (((row) & 7) << 4))
#define SIN_SC 0.5968310366f   // 3.75 / (2*pi)

__global__ __launch_bounds__(256, 2)
void attn_kernel(const unsigned short* __restrict__ Qg,
                 const unsigned short* __restrict__ Kg,
                 const unsigned short* __restrict__ Vg,   // Vt[b][n][s]
                 unsigned short* __restrict__ AO)
{
    __shared__ unsigned short Ps[8192];       // [128 q][64 k], 16KB

    const int t = threadIdx.x;
    const int lane = t & 63;
    const int g = lane >> 4;
    const int c = lane & 15;
    const int w = t >> 6;

    // XCD-chunked bijective swizzle: 512 blocks, chunk 64 per XCD
    const int bid = blockIdx.x;
    const int lb = (bid & 7) * 64 + (bid >> 3);
    const int qb = lb & 15;
    const int h = (lb >> 4) & 15;
    const int b = lb >> 8;
    const int qbase = qb * 128;

    char* const Psb = (char*)Ps;

    // Q fragments in registers (loop-invariant): qreg[kk][qi]
    fragAB qreg[2][8];
#pragma unroll
    for (int kk = 0; kk < 2; ++kk)
#pragma unroll
        for (int qi = 0; qi < 8; ++qi)
            qreg[kk][qi] = *(const fragAB*)(Qg + (size_t)(b * 2048 + qbase + qi * 16 + c) * 1024
                                            + h * 64 + kk * 32 + g * 8);

    // direct-load fragment bases
    const unsigned short* Kbase = Kg + (size_t)(b * 2048 + 16 * w + c) * 1024 + h * 64 + g * 8;
    const unsigned short* Vbase = Vg + ((size_t)b * 1024 + h * 64 + c) * 2048 + g * 8;

    const f32x4 z = {0.f, 0.f, 0.f, 0.f};
    f32x4 o[2][4];
#pragma unroll
    for (int mi = 0; mi < 2; ++mi)
#pragma unroll
        for (int ni = 0; ni < 4; ++ni) o[mi][ni] = z;

    const int pkbyte = 32 * w + 8 * g;   // P k-byte offset for this lane's C rows

    // prologue: K chunk 0 into kfA
    fragAB kfA[2], kfB[2];
    kfA[0] = *(const fragAB*)(Kbase);
    kfA[1] = *(const fragAB*)(Kbase + 32);

    auto body = [&](int kb, fragAB (&kfc)[2], fragAB (&kfn)[2]) {
        // prefetch K(kb+1)
        if (kb < 31) {
            kfn[0] = *(const fragAB*)(Kbase + (size_t)(kb + 1) * 65536);
            kfn[1] = *(const fragAB*)(Kbase + (size_t)(kb + 1) * 65536 + 32);
        }
        // V(kb) fragments -> regs (consumed after barrier, ~QK+sin of latency cover)
        fragAB vf[2][4];
#pragma unroll
        for (int kk = 0; kk < 2; ++kk)
#pragma unroll
            for (int ni = 0; ni < 4; ++ni)
                vf[kk][ni] = *(const fragAB*)(Vbase + (size_t)(ni * 16) * 2048 + kb * 64 + kk * 32);

        // QK(kb): St = K*Q^T, wave w owns k rows [16w,16w+16), q 0..127
        f32x4 st[8];
#pragma unroll
        for (int qi = 0; qi < 8; ++qi) st[qi] = z;
#pragma unroll
        for (int qi = 0; qi < 8; ++qi) {
            st[qi] = MFMA(kfc[0], qreg[0][qi], st[qi]);
            st[qi] = MFMA(kfc[1], qreg[1][qi], st[qi]);
        }

        // sin -> P[q][k]
#pragma unroll
        for (int qi = 0; qi < 8; ++qi) {
            const int q = qi * 16 + c;
            float s0 = fsin_rev(st[qi][0] * SIN_SC);
            float s1 = fsin_rev(st[qi][1] * SIN_SC);
            float s2 = fsin_rev(st[qi][2] * SIN_SC);
            float s3 = fsin_rev(st[qi][3] * SIN_SC);
            uint2 pk;
            pk.x = cvtpk(s0, s1);
            pk.y = cvtpk(s2, s3);
            *(uint2*)(Psb + SWZ(q * 128 + pkbyte, q)) = pk;
        }

        asm volatile("s_waitcnt lgkmcnt(0)" ::: "memory");  // P visible
        __builtin_amdgcn_s_barrier();

        // PV(kb): wave w owns q rows [32w,32w+32), d 0..63
#pragma unroll
        for (int kk = 0; kk < 2; ++kk) {
            fragAB pf[2];
#pragma unroll
            for (int mi = 0; mi < 2; ++mi) {
                const int q = 32 * w + mi * 16 + c;
                pf[mi] = *(const fragAB*)(Psb + SWZ(q * 128 + kk * 64 + g * 16, q));
            }
#pragma unroll
            for (int mi = 0; mi < 2; ++mi)
#pragma unroll
                for (int ni = 0; ni < 4; ++ni)
                    o[mi][ni] = MFMA(pf[mi], vf[kk][ni], o[mi][ni]);
        }

        __builtin_amdgcn_s_barrier();   // P readers done -> next iter may overwrite
    };

    for (int tt = 0; tt < 16; ++tt) {
        body(2 * tt,     kfA, kfB);
        body(2 * tt + 1, kfB, kfA);
    }

#pragma unroll
    for (int mi = 0; mi < 2; ++mi)
#pragma unroll
        for (int ni = 0; ni < 4; ++ni) {
            const int dd = ni * 16 + c;
#pragma unroll
            for (int j = 0; j < 4; ++j) {
                const int q = qbase + 32 * w + mi * 16 + g * 4 + j;
                AO[(size_t)(b * 2048 + q) * 1024 + h * 64 + dd] = f2bf(o[mi][ni][j]);
            }
        }
}

// ---------- launcher ----------
extern "C" void kernel_launch(void* const* d_in, const int* in_sizes, int n_in,
                              void* d_out, int out_size, void* d_ws, size_t ws_size,
                              hipStream_t stream) {
    (void)in_sizes; (void)n_in; (void)out_size; (void)ws_size;
    const float* x  = (const float*)d_in[0];
    const float* Wq = (const float*)d_in[1];
    const float* bq = (const float*)d_in[2];
    const float* Wk = (const float*)d_in[3];
    const float* bk = (const float*)d_in[4];
    const float* Wv = (const float*)d_in[5];
    const float* bv = (const float*)d_in[6];
    const float* Wo = (const float*)d_in[7];
    const float* bo = (const float*)d_in[8];

    char* ws = (char*)d_ws;
    unsigned short* xb  = (unsigned short*)(ws);                    // 8MB
    unsigned short* Wqb = (unsigned short*)(ws + (8u  << 20));      // 2MB each
    unsigned short* Wkb = (unsigned short*)(ws + (10u << 20));
    unsigned short* Wvb = (unsigned short*)(ws + (12u << 20));
    unsigned short* Wob = (unsigned short*)(ws + (14u << 20));
    unsigned short* Qb  = (unsigned short*)(ws + (16u << 20));      // 8MB
    unsigned short* Kb  = (unsigned short*)(ws + (24u << 20));      // 8MB
    unsigned short* Vtb = (unsigned short*)(ws + (32u << 20));      // 8MB, [b][n][s]
    unsigned short* AO  = (unsigned short*)(ws + (40u << 20));      // 8MB

    cvt_all<<<8192, 256, 0, stream>>>(x, Wq, Wk, Wv, Wo, xb, Wqb, Wkb, Wvb, Wob);

    gemm_k<<<dim3(8, 32, 3), 256, 0, stream>>>(xb, Wqb, Wkb, Wvb, bq, bk, bv,
                                               Qb, Kb, Vtb);

    attn_kernel<<<512, 256, 0, stream>>>(Qb, Kb, Vtb, AO);

    gemm64<<<dim3(8, 64), 256, 0, stream>>>(AO, Wob, bo, (float*)d_out);
}

// Round 6
// 106.765 us; speedup vs baseline: 1.3622x; 1.3622x over previous
//
#include <hip/hip_runtime.h>
#include <stdint.h>

// ---------- types ----------
typedef __attribute__((ext_vector_type(8))) __bf16 fragAB;   // 8 bf16 = 4 VGPR
typedef __attribute__((ext_vector_type(4))) float f32x4;
typedef __attribute__((ext_vector_type(16))) float f32x16;
typedef __attribute__((ext_vector_type(4))) unsigned int u32x4;

__device__ __forceinline__ unsigned short f2bf(float f) {
    union { float f; unsigned int u; } v; v.f = f;
    unsigned int u = v.u + 0x7fffu + ((v.u >> 16) & 1u);   // RNE
    return (unsigned short)(u >> 16);
}

__device__ __forceinline__ f32x4 MFMA16(fragAB a, fragAB b, f32x4 c) {
    return __builtin_amdgcn_mfma_f32_16x16x32_bf16(a, b, c, 0, 0, 0);
}
__device__ __forceinline__ f32x16 MFMA32(fragAB a, fragAB b, f32x16 c) {
    return __builtin_amdgcn_mfma_f32_32x32x16_bf16(a, b, c, 0, 0, 0);
}

// async global->LDS, 16B per lane; LDS dest = wave-uniform base + lane*16
__device__ __forceinline__ void gl16(const void* g, void* l) {
    __builtin_amdgcn_global_load_lds((const __attribute__((address_space(1))) void*)g,
                                     (__attribute__((address_space(3))) void*)l, 16, 0, 0);
}

__device__ __forceinline__ float fsin_rev(float rev) {   // sin(2*pi*rev)
    float r; asm("v_sin_f32 %0, %1" : "=v"(r) : "v"(rev)); return r;
}
__device__ __forceinline__ unsigned int cvtpk(float lo, float hi) {  // 2xbf16 RNE
    unsigned int r; asm("v_cvt_pk_bf16_f32 %0, %1, %2" : "=v"(r) : "v"(lo), "v"(hi)); return r;
}
__device__ __forceinline__ void swap32(unsigned int& a, unsigned int& b) {
    // exchanges a's lanes 32-63 with b's lanes 0-31
    asm volatile("v_permlane32_swap_b32 %0, %1" : "+v"(a), "+v"(b));
}

#define SIN_SC 0.5968310366f   // 3.75 / (2*pi)

// ---------- fused fp32 -> bf16 convert (x + 4 weights in one launch) ----------
__global__ __launch_bounds__(256) void cvt_all(
    const float* __restrict__ x,  const float* __restrict__ wq, const float* __restrict__ wk,
    const float* __restrict__ wv, const float* __restrict__ wo,
    unsigned short* __restrict__ xb,  unsigned short* __restrict__ wqb, unsigned short* __restrict__ wkb,
    unsigned short* __restrict__ wvb, unsigned short* __restrict__ wob)
{
    const int bid = blockIdx.x;
    const float* s; unsigned short* d; int off;
    if (bid < 4096)      { s = x;  d = xb;  off = bid; }
    else if (bid < 5120) { s = wq; d = wqb; off = bid - 4096; }
    else if (bid < 6144) { s = wk; d = wkb; off = bid - 5120; }
    else if (bid < 7168) { s = wv; d = wvb; off = bid - 6144; }
    else                 { s = wo; d = wob; off = bid - 7168; }
    const int i = (off * 256 + threadIdx.x) * 4;
    float4 f = *(const float4*)(s + i);
    ushort4 o;
    o.x = f2bf(f.x); o.y = f2bf(f.y); o.z = f2bf(f.z); o.w = f2bf(f.w);
    *(ushort4*)(d + i) = o;
}

// ---------- GEMM (m97 structure, 128x128): Q/K/V projections ----------
// z=0: Q row-major bf16. z=1: K scattered into MFMA-fragment order (Kshuf).
// z=2: V scattered into MFMA-fragment order (Vshuf).
// Kshuf block (b,h,kb,kbl,ds): 1KB: lane l holds K[s=b*2048+kb*64+kbl*32+(l&31)]
//                                   [d=h*64+ds*16+(l>>5)*8+e], e=0..7
// Vshuf block (b,h,kb,ks,ni):  1KB: lane l holds V[s=b*2048+kb*64+ks*16+(l>>5)*8+e]
//                                   [d=h*64+ni*32+(l&31)]
__global__ __launch_bounds__(256, 2)
void gemm_k(const unsigned short* __restrict__ A,
            const unsigned short* __restrict__ W0, const unsigned short* __restrict__ W1,
            const unsigned short* __restrict__ W2,
            const float* __restrict__ b0, const float* __restrict__ b1, const float* __restrict__ b2,
            void* o0, void* o1, void* o2)
{
    __shared__ unsigned short As[8192];   // [128][64] linear, 16KB
    __shared__ unsigned short Ws[8192];

    const int z = blockIdx.z;
    const unsigned short* W = z == 0 ? W0 : (z == 1 ? W1 : W2);
    const float* bias        = z == 0 ? b0 : (z == 1 ? b1 : b2);
    void* out                = z == 0 ? o0 : (z == 1 ? o1 : o2);

    const int t = threadIdx.x;
    const int lane = t & 63;
    const int g = lane >> 4;
    const int c = lane & 15;
    const int w = t >> 6;
    const int wm = (w >> 1) * 64;
    const int wn = (w & 1) * 64;
    const int m0 = blockIdx.y * 128;
    const int n0 = blockIdx.x * 128;

    const int srow = lane >> 3;
    const int scol = (lane & 7) * 8;

    const f32x4 zz = {0.f, 0.f, 0.f, 0.f};
    f32x4 acc[4][4];
#pragma unroll
    for (int mi = 0; mi < 4; ++mi)
#pragma unroll
        for (int ni = 0; ni < 4; ++ni) acc[mi][ni] = zz;

    for (int kt = 0; kt < 16; ++kt) {
        const int k0 = kt * 64;
#pragma unroll
        for (int r = 0; r < 4; ++r) {
            gl16(A + (size_t)(m0 + 32 * w + 8 * r + srow) * 1024 + k0 + scol,
                 (unsigned short*)As + (w * 4 + r) * 512);
            gl16(W + (size_t)(n0 + 32 * w + 8 * r + srow) * 1024 + k0 + scol,
                 (unsigned short*)Ws + (w * 4 + r) * 512);
        }
        __syncthreads();
#pragma unroll
        for (int kk = 0; kk < 2; ++kk) {
            fragAB af[4], bfr[4];
#pragma unroll
            for (int mi = 0; mi < 4; ++mi)
                af[mi] = *(const fragAB*)((char*)As + (wm + mi * 16 + c) * 128 + kk * 64 + g * 16);
#pragma unroll
            for (int ni = 0; ni < 4; ++ni)
                bfr[ni] = *(const fragAB*)((char*)Ws + (wn + ni * 16 + c) * 128 + kk * 64 + g * 16);
#pragma unroll
            for (int mi = 0; mi < 4; ++mi)
#pragma unroll
                for (int ni = 0; ni < 4; ++ni)
                    acc[mi][ni] = MFMA16(af[mi], bfr[ni], acc[mi][ni]);
        }
        __syncthreads();
    }

    float bv[4];
#pragma unroll
    for (int ni = 0; ni < 4; ++ni) bv[ni] = bias[n0 + wn + ni * 16 + c];

    if (z == 0) {                                // Q: row-major bf16
        unsigned short* C = (unsigned short*)out;
#pragma unroll
        for (int mi = 0; mi < 4; ++mi)
#pragma unroll
            for (int ni = 0; ni < 4; ++ni)
#pragma unroll
                for (int j = 0; j < 4; ++j) {
                    const int grow = m0 + wm + mi * 16 + g * 4 + j;
                    const int gcol = n0 + wn + ni * 16 + c;
                    C[(size_t)grow * 1024 + gcol] = f2bf(acc[mi][ni][j] + bv[ni]);
                }
    } else if (z == 1) {                         // Kshuf scatter (2B stores)
        unsigned short* Ksh = (unsigned short*)out;
#pragma unroll
        for (int mi = 0; mi < 4; ++mi) {
            const int s0 = m0 + wm + mi * 16 + g * 4;
            const int b_ = s0 >> 11, sr = s0 & 2047;
            const int kb = sr >> 6, kbl = (sr >> 5) & 1;
            const int l31b = (mi & 1) * 16 + g * 4;
#pragma unroll
            for (int ni = 0; ni < 4; ++ni) {
                const int n = n0 + wn + ni * 16 + c;
                const int h_ = n >> 6, d = n & 63;
                const int ds = d >> 4, e = d & 7, lhalf = (d >> 3) & 1;
                const size_t base =
                    ((((size_t)(b_ * 16 + h_) * 32 + kb) * 2 + kbl) * 4 + ds) * 512
                    + lhalf * 256 + (size_t)l31b * 8 + e;
#pragma unroll
                for (int j = 0; j < 4; ++j)
                    Ksh[base + j * 8] = f2bf(acc[mi][ni][j] + bv[ni]);
            }
        }
    } else {                                     // Vshuf scatter (8B stores)
        unsigned short* Vsh = (unsigned short*)out;
#pragma unroll
        for (int mi = 0; mi < 4; ++mi) {
            const int s0 = m0 + wm + mi * 16 + g * 4;
            const int b_ = s0 >> 11, sr = s0 & 2047;
            const int kb = sr >> 6;
            const int kslice = mi;               // (mi*16+g*4)>>4
            const int khalf = (g >> 1) & 1;
            const int e0 = (g & 1) * 4;
#pragma unroll
            for (int ni = 0; ni < 4; ++ni) {
                const int n = n0 + wn + ni * 16 + c;
                const int h_ = n >> 6;
                const int nei = ni >> 1;
                const int l31 = (ni & 1) * 16 + c;
                const size_t base =
                    ((((size_t)(b_ * 16 + h_) * 32 + kb) * 4 + kslice) * 2 + nei) * 512
                    + (size_t)(khalf * 32 + l31) * 8 + e0;
                ushort4 pk;
                pk.x = f2bf(acc[mi][ni][0] + bv[ni]);
                pk.y = f2bf(acc[mi][ni][1] + bv[ni]);
                pk.z = f2bf(acc[mi][ni][2] + bv[ni]);
                pk.w = f2bf(acc[mi][ni][3] + bv[ni]);
                *(ushort4*)(Vsh + base) = pk;
            }
        }
    }
}

// ---------- GEMM 64x128 tile, fp32 out: final projection ----------
__global__ __launch_bounds__(256, 4)
void gemm64(const unsigned short* __restrict__ A,
            const unsigned short* __restrict__ W,
            const float* __restrict__ bias, float* __restrict__ out)
{
    __shared__ unsigned short As[4096];   // [64][64]  8KB
    __shared__ unsigned short Ws[8192];   // [128][64] 16KB

    const int t = threadIdx.x;
    const int lane = t & 63;
    const int g = lane >> 4;
    const int c = lane & 15;
    const int w = t >> 6;
    const int wm = (w >> 1) * 32;
    const int wn = (w & 1) * 64;
    const int m0 = blockIdx.y * 64;
    const int n0 = blockIdx.x * 128;

    const int srow = lane >> 3;
    const int scol = (lane & 7) * 8;

    const f32x4 zz = {0.f, 0.f, 0.f, 0.f};
    f32x4 acc[2][4];
#pragma unroll
    for (int mi = 0; mi < 2; ++mi)
#pragma unroll
        for (int ni = 0; ni < 4; ++ni) acc[mi][ni] = zz;

    for (int kt = 0; kt < 16; ++kt) {
        const int k0 = kt * 64;
        gl16(A + (size_t)(m0 + 16 * w + srow) * 1024 + k0 + scol,
             (unsigned short*)As + (2 * w) * 512);
        gl16(A + (size_t)(m0 + 16 * w + 8 + srow) * 1024 + k0 + scol,
             (unsigned short*)As + (2 * w + 1) * 512);
#pragma unroll
        for (int r = 0; r < 4; ++r)
            gl16(W + (size_t)(n0 + 32 * w + 8 * r + srow) * 1024 + k0 + scol,
                 (unsigned short*)Ws + (w * 4 + r) * 512);
        __syncthreads();
#pragma unroll
        for (int kk = 0; kk < 2; ++kk) {
            fragAB af[2], bfr[4];
#pragma unroll
            for (int mi = 0; mi < 2; ++mi)
                af[mi] = *(const fragAB*)((char*)As + (wm + mi * 16 + c) * 128 + kk * 64 + g * 16);
#pragma unroll
            for (int ni = 0; ni < 4; ++ni)
                bfr[ni] = *(const fragAB*)((char*)Ws + (wn + ni * 16 + c) * 128 + kk * 64 + g * 16);
#pragma unroll
            for (int mi = 0; mi < 2; ++mi)
#pragma unroll
                for (int ni = 0; ni < 4; ++ni)
                    acc[mi][ni] = MFMA16(af[mi], bfr[ni], acc[mi][ni]);
        }
        __syncthreads();
    }

#pragma unroll
    for (int ni = 0; ni < 4; ++ni) {
        const float bv = bias[n0 + wn + ni * 16 + c];
#pragma unroll
        for (int mi = 0; mi < 2; ++mi)
#pragma unroll
            for (int j = 0; j < 4; ++j) {
                const int grow = m0 + wm + mi * 16 + g * 4 + j;
                const int gcol = n0 + wn + ni * 16 + c;
                out[(size_t)grow * 1024 + gcol] = acc[mi][ni][j] + bv;
            }
    }
}

// ---------- fused sine attention v3: 32x32 MFMA, fragment-order LDS, reg P ----------
// QBLK=128, KVBLK=64. 4 waves = 2 q-halves x 2 k-halves (k-split, O reduced at end).
// St = K*Q^T per wave (32q x 32k own); P built in registers via cvt_pk + permlane32_swap;
// PV from reg-P x LDS V-frags. LDS frag reads are lane*16 -> conflict-free.
// One __syncthreads per iter (staging dbuf); prefetch issued a full iter early.
__global__ __launch_bounds__(256, 2)
void attn_kernel(const unsigned short* __restrict__ Qg,
                 const unsigned short* __restrict__ Ksh,
                 const unsigned short* __restrict__ Vsh,
                 unsigned short* __restrict__ AO)
{
    __shared__ char smem[32768];
    unsigned short* const KldsU = (unsigned short*)smem;            // 2 bufs x 8KB
    unsigned short* const VldsU = (unsigned short*)(smem + 16384);  // 2 bufs x 8KB
    float* const red = (float*)smem;                                // reduce scratch

    const int t = threadIdx.x;
    const int lane = t & 63;
    const int l31 = lane & 31;
    const int lh = lane >> 5;
    const int w = t >> 6;
    const int qh = w >> 1;     // q-half owned
    const int kbl = w & 1;     // k-half owned

    // XCD-chunked bijective swizzle (512 blocks, 64 per XCD -> (b,h) stays on one XCD)
    const int bid = blockIdx.x;
    const int lb = (bid & 7) * 64 + (bid >> 3);
    const int qb = lb & 15;
    const int h = (lb >> 4) & 15;
    const int b = lb >> 8;
    const int qbase = qb * 128;

    const unsigned short* Kc = Ksh + (size_t)(b * 16 + h) * 131072;   // 32kb x 8blk x 512us
    const unsigned short* Vc = Vsh + (size_t)(b * 16 + h) * 131072;

    // Q fragments (loop-invariant): qf[qi][ds], lane holds Q[qown+ (l&31)][ds*16+(l>>5)*8..]
    fragAB qf[2][4];
#pragma unroll
    for (int qi = 0; qi < 2; ++qi)
#pragma unroll
        for (int ds = 0; ds < 4; ++ds)
            qf[qi][ds] = *(const fragAB*)(Qg
                + (size_t)(b * 2048 + qbase + qh * 64 + qi * 32 + l31) * 1024
                + h * 64 + ds * 16 + lh * 8);

    f32x16 o[2][2];
#pragma unroll
    for (int qi = 0; qi < 2; ++qi)
#pragma unroll
        for (int ni = 0; ni < 2; ++ni)
#pragma unroll
            for (int r = 0; r < 16; ++r) o[qi][ni][r] = 0.f;

    const int blk0 = 2 * w, blk1 = 2 * w + 1;

    // prologue: stage kb=0 into buf 0
    gl16(Kc + blk0 * 512 + lane * 8, KldsU + blk0 * 512);
    gl16(Kc + blk1 * 512 + lane * 8, KldsU + blk1 * 512);
    gl16(Vc + blk0 * 512 + lane * 8, VldsU + blk0 * 512);
    gl16(Vc + blk1 * 512 + lane * 8, VldsU + blk1 * 512);
    __syncthreads();

    for (int kb = 0; kb < 32; ++kb) {
        const int buf = kb & 1;

        if (kb < 31) {   // prefetch kb+1 into buf^1 (drained by bottom syncthreads)
            const int nb = buf ^ 1;
            const size_t so = (size_t)(kb + 1) * 4096;
            gl16(Kc + so + blk0 * 512 + lane * 8, KldsU + nb * 4096 + blk0 * 512);
            gl16(Kc + so + blk1 * 512 + lane * 8, KldsU + nb * 4096 + blk1 * 512);
            gl16(Vc + so + blk0 * 512 + lane * 8, VldsU + nb * 4096 + blk0 * 512);
            gl16(Vc + so + blk1 * 512 + lane * 8, VldsU + nb * 4096 + blk1 * 512);
        }

        // conflict-free frag reads (lane*16B each)
        fragAB kf[4];
#pragma unroll
        for (int ds = 0; ds < 4; ++ds)
            kf[ds] = *(const fragAB*)(KldsU + buf * 4096 + (kbl * 4 + ds) * 512 + lane * 8);
        fragAB vf[2][2];
#pragma unroll
        for (int ks = 0; ks < 2; ++ks)
#pragma unroll
            for (int ni = 0; ni < 2; ++ni)
                vf[ks][ni] = *(const fragAB*)(VldsU + buf * 4096
                                              + ((kbl * 2 + ks) * 2 + ni) * 512 + lane * 8);

        // QK: St[qi] = K(own 32k) . Q(own 32q)^T over d=64
        f32x16 st[2];
#pragma unroll
        for (int qi = 0; qi < 2; ++qi)
#pragma unroll
            for (int r = 0; r < 16; ++r) st[qi][r] = 0.f;
        __builtin_amdgcn_s_setprio(1);
#pragma unroll
        for (int qi = 0; qi < 2; ++qi)
#pragma unroll
            for (int ds = 0; ds < 4; ++ds)
                st[qi] = MFMA32(kf[ds], qf[qi][ds], st[qi]);
        __builtin_amdgcn_s_setprio(0);

        // per qi: sin -> bf16 pairs -> permlane32_swap -> PV A-frags -> PV
#pragma unroll
        for (int qi = 0; qi < 2; ++qi) {
            unsigned int u[8];
#pragma unroll
            for (int i = 0; i < 8; ++i)
                u[i] = cvtpk(fsin_rev(st[qi][2 * i] * SIN_SC),
                             fsin_rev(st[qi][2 * i + 1] * SIN_SC));
            swap32(u[0], u[2]); swap32(u[1], u[3]);
            swap32(u[4], u[6]); swap32(u[5], u[7]);
            union { u32x4 u; fragAB f; } pa0, pa1;
            pa0.u = (u32x4){u[0], u[1], u[2], u[3]};
            pa1.u = (u32x4){u[4], u[5], u[6], u[7]};
            __builtin_amdgcn_s_setprio(1);
#pragma unroll
            for (int ni = 0; ni < 2; ++ni) {
                o[qi][ni] = MFMA32(pa0.f, vf[0][ni], o[qi][ni]);
                o[qi][ni] = MFMA32(pa1.f, vf[1][ni], o[qi][ni]);
            }
            __builtin_amdgcn_s_setprio(0);
        }

        __syncthreads();   // next buf staged; this buf's readers done
    }

    // cross-k-half reduce: odd waves write partial O, even waves add + store
    if (kbl) {
#pragma unroll
        for (int qi = 0; qi < 2; ++qi)
#pragma unroll
            for (int ni = 0; ni < 2; ++ni)
#pragma unroll
                for (int r = 0; r < 16; ++r)
                    red[(((qh * 2 + qi) * 2 + ni) * 16 + r) * 64 + lane] = o[qi][ni][r];
    }
    __syncthreads();
    if (!kbl) {
#pragma unroll
        for (int qi = 0; qi < 2; ++qi)
#pragma unroll
            for (int ni = 0; ni < 2; ++ni)
#pragma unroll
                for (int r = 0; r < 16; ++r) {
                    const float v = o[qi][ni][r]
                        + red[(((qh * 2 + qi) * 2 + ni) * 16 + r) * 64 + lane];
                    const int q = qbase + qh * 64 + qi * 32 + (r & 3) + 8 * (r >> 2) + 4 * lh;
                    AO[(size_t)(b * 2048 + q) * 1024 + h * 64 + ni * 32 + l31] = f2bf(v);
                }
    }
}

// ---------- launcher ----------
extern "C" void kernel_launch(void* const* d_in, const int* in_sizes, int n_in,
                              void* d_out, int out_size, void* d_ws, size_t ws_size,
                              hipStream_t stream) {
    (void)in_sizes; (void)n_in; (void)out_size; (void)ws_size;
    const float* x  = (const float*)d_in[0];
    const float* Wq = (const float*)d_in[1];
    const float* bq = (const float*)d_in[2];
    const float* Wk = (const float*)d_in[3];
    const float* bk = (const float*)d_in[4];
    const float* Wv = (const float*)d_in[5];
    const float* bv = (const float*)d_in[6];
    const float* Wo = (const float*)d_in[7];
    const float* bo = (const float*)d_in[8];

    char* ws = (char*)d_ws;
    unsigned short* xb    = (unsigned short*)(ws);                    // 8MB
    unsigned short* Wqb   = (unsigned short*)(ws + (8u  << 20));      // 2MB each
    unsigned short* Wkb   = (unsigned short*)(ws + (10u << 20));
    unsigned short* Wvb   = (unsigned short*)(ws + (12u << 20));
    unsigned short* Wob   = (unsigned short*)(ws + (14u << 20));
    unsigned short* Qb    = (unsigned short*)(ws + (16u << 20));      // 8MB row-major
    unsigned short* Kshuf = (unsigned short*)(ws + (24u << 20));      // 8MB frag-order
    unsigned short* Vshuf = (unsigned short*)(ws + (32u << 20));      // 8MB frag-order
    unsigned short* AO    = (unsigned short*)(ws + (40u << 20));      // 8MB row-major

    cvt_all<<<8192, 256, 0, stream>>>(x, Wq, Wk, Wv, Wo, xb, Wqb, Wkb, Wvb, Wob);

    gemm_k<<<dim3(8, 32, 3), 256, 0, stream>>>(xb, Wqb, Wkb, Wvb, bq, bk, bv,
                                               Qb, Kshuf, Vshuf);

    attn_kernel<<<512, 256, 0, stream>>>(Qb, Kshuf, Vshuf, AO);

    gemm64<<<dim3(8, 64), 256, 0, stream>>>(AO, Wob, bo, (float*)d_out);
}

// Round 8
// 104.597 us; speedup vs baseline: 1.3904x; 1.0207x over previous
//
#include <hip/hip_runtime.h>
#include <stdint.h>

// ---------- types ----------
typedef __attribute__((ext_vector_type(8))) __bf16 fragAB;   // 8 bf16 = 4 VGPR
typedef __attribute__((ext_vector_type(4))) float f32x4;
typedef __attribute__((ext_vector_type(16))) float f32x16;
typedef __attribute__((ext_vector_type(4))) unsigned int u32x4;

__device__ __forceinline__ unsigned short f2bf(float f) {
    union { float f; unsigned int u; } v; v.f = f;
    unsigned int u = v.u + 0x7fffu + ((v.u >> 16) & 1u);   // RNE
    return (unsigned short)(u >> 16);
}

__device__ __forceinline__ f32x4 MFMA16(fragAB a, fragAB b, f32x4 c) {
    return __builtin_amdgcn_mfma_f32_16x16x32_bf16(a, b, c, 0, 0, 0);
}
__device__ __forceinline__ f32x16 MFMA32(fragAB a, fragAB b, f32x16 c) {
    return __builtin_amdgcn_mfma_f32_32x32x16_bf16(a, b, c, 0, 0, 0);
}

// async global->LDS, 16B per lane; LDS dest = wave-uniform base + lane*16
__device__ __forceinline__ void gl16(const void* g, void* l) {
    __builtin_amdgcn_global_load_lds((const __attribute__((address_space(1))) void*)g,
                                     (__attribute__((address_space(3))) void*)l, 16, 0, 0);
}

__device__ __forceinline__ float fsin_rev(float rev) {   // sin(2*pi*rev)
    float r; asm("v_sin_f32 %0, %1" : "=v"(r) : "v"(rev)); return r;
}
__device__ __forceinline__ unsigned int cvtpk(float lo, float hi) {  // 2xbf16 RNE
    unsigned int r; asm("v_cvt_pk_bf16_f32 %0, %1, %2" : "=v"(r) : "v"(lo), "v"(hi)); return r;
}
__device__ __forceinline__ void swap32(unsigned int& a, unsigned int& b) {
    // exchanges a's lanes 32-63 with b's lanes 0-31
    asm volatile("v_permlane32_swap_b32 %0, %1" : "+v"(a), "+v"(b));
}

#define SIN_SC 0.5968310366f   // 3.75 / (2*pi)

// ---------- fused fp32 -> bf16 convert (x + 4 weights in one launch) ----------
__global__ __launch_bounds__(256) void cvt_all(
    const float* __restrict__ x,  const float* __restrict__ wq, const float* __restrict__ wk,
    const float* __restrict__ wv, const float* __restrict__ wo,
    unsigned short* __restrict__ xb,  unsigned short* __restrict__ wqb, unsigned short* __restrict__ wkb,
    unsigned short* __restrict__ wvb, unsigned short* __restrict__ wob)
{
    const int bid = blockIdx.x;
    const float* s; unsigned short* d; int off;
    if (bid < 4096)      { s = x;  d = xb;  off = bid; }
    else if (bid < 5120) { s = wq; d = wqb; off = bid - 4096; }
    else if (bid < 6144) { s = wk; d = wkb; off = bid - 5120; }
    else if (bid < 7168) { s = wv; d = wvb; off = bid - 6144; }
    else                 { s = wo; d = wob; off = bid - 7168; }
    const int i = (off * 256 + threadIdx.x) * 4;
    float4 f = *(const float4*)(s + i);
    ushort4 o;
    o.x = f2bf(f.x); o.y = f2bf(f.y); o.z = f2bf(f.z); o.w = f2bf(f.w);
    *(ushort4*)(d + i) = o;
}

// ---------- GEMM (m97 structure, 128x128): Q/K/V projections ----------
// z=0: Q row-major bf16 (UNSCALED, R6 form). z=1: Kshuf. z=2: Vshuf (frag order).
__global__ __launch_bounds__(256, 2)
void gemm_k(const unsigned short* __restrict__ A,
            const unsigned short* __restrict__ W0, const unsigned short* __restrict__ W1,
            const unsigned short* __restrict__ W2,
            const float* __restrict__ b0, const float* __restrict__ b1, const float* __restrict__ b2,
            void* o0, void* o1, void* o2)
{
    __shared__ unsigned short As[8192];   // [128][64] linear, 16KB
    __shared__ unsigned short Ws[8192];

    const int z = blockIdx.z;
    const unsigned short* W = z == 0 ? W0 : (z == 1 ? W1 : W2);
    const float* bias        = z == 0 ? b0 : (z == 1 ? b1 : b2);
    void* out                = z == 0 ? o0 : (z == 1 ? o1 : o2);

    const int t = threadIdx.x;
    const int lane = t & 63;
    const int g = lane >> 4;
    const int c = lane & 15;
    const int w = t >> 6;
    const int wm = (w >> 1) * 64;
    const int wn = (w & 1) * 64;
    const int m0 = blockIdx.y * 128;
    const int n0 = blockIdx.x * 128;

    const int srow = lane >> 3;
    const int scol = (lane & 7) * 8;

    const f32x4 zz = {0.f, 0.f, 0.f, 0.f};
    f32x4 acc[4][4];
#pragma unroll
    for (int mi = 0; mi < 4; ++mi)
#pragma unroll
        for (int ni = 0; ni < 4; ++ni) acc[mi][ni] = zz;

    for (int kt = 0; kt < 16; ++kt) {
        const int k0 = kt * 64;
#pragma unroll
        for (int r = 0; r < 4; ++r) {
            gl16(A + (size_t)(m0 + 32 * w + 8 * r + srow) * 1024 + k0 + scol,
                 (unsigned short*)As + (w * 4 + r) * 512);
            gl16(W + (size_t)(n0 + 32 * w + 8 * r + srow) * 1024 + k0 + scol,
                 (unsigned short*)Ws + (w * 4 + r) * 512);
        }
        __syncthreads();
#pragma unroll
        for (int kk = 0; kk < 2; ++kk) {
            fragAB af[4], bfr[4];
#pragma unroll
            for (int mi = 0; mi < 4; ++mi)
                af[mi] = *(const fragAB*)((char*)As + (wm + mi * 16 + c) * 128 + kk * 64 + g * 16);
#pragma unroll
            for (int ni = 0; ni < 4; ++ni)
                bfr[ni] = *(const fragAB*)((char*)Ws + (wn + ni * 16 + c) * 128 + kk * 64 + g * 16);
#pragma unroll
            for (int mi = 0; mi < 4; ++mi)
#pragma unroll
                for (int ni = 0; ni < 4; ++ni)
                    acc[mi][ni] = MFMA16(af[mi], bfr[ni], acc[mi][ni]);
        }
        __syncthreads();
    }

    float bv[4];
#pragma unroll
    for (int ni = 0; ni < 4; ++ni) bv[ni] = bias[n0 + wn + ni * 16 + c];

    if (z == 0) {                                // Q: row-major bf16 (unscaled)
        unsigned short* C = (unsigned short*)out;
#pragma unroll
        for (int mi = 0; mi < 4; ++mi)
#pragma unroll
            for (int ni = 0; ni < 4; ++ni)
#pragma unroll
                for (int j = 0; j < 4; ++j) {
                    const int grow = m0 + wm + mi * 16 + g * 4 + j;
                    const int gcol = n0 + wn + ni * 16 + c;
                    C[(size_t)grow * 1024 + gcol] = f2bf(acc[mi][ni][j] + bv[ni]);
                }
    } else if (z == 1) {                         // Kshuf scatter (2B stores)
        unsigned short* Ksh = (unsigned short*)out;
#pragma unroll
        for (int mi = 0; mi < 4; ++mi) {
            const int s0 = m0 + wm + mi * 16 + g * 4;
            const int b_ = s0 >> 11, sr = s0 & 2047;
            const int kb = sr >> 6, kbl = (sr >> 5) & 1;
            const int l31b = (mi & 1) * 16 + g * 4;
#pragma unroll
            for (int ni = 0; ni < 4; ++ni) {
                const int n = n0 + wn + ni * 16 + c;
                const int h_ = n >> 6, d = n & 63;
                const int ds = d >> 4, e = d & 7, lhalf = (d >> 3) & 1;
                const size_t base =
                    ((((size_t)(b_ * 16 + h_) * 32 + kb) * 2 + kbl) * 4 + ds) * 512
                    + lhalf * 256 + (size_t)l31b * 8 + e;
#pragma unroll
                for (int j = 0; j < 4; ++j)
                    Ksh[base + j * 8] = f2bf(acc[mi][ni][j] + bv[ni]);
            }
        }
    } else {                                     // Vshuf scatter (8B stores)
        unsigned short* Vsh = (unsigned short*)out;
#pragma unroll
        for (int mi = 0; mi < 4; ++mi) {
            const int s0 = m0 + wm + mi * 16 + g * 4;
            const int b_ = s0 >> 11, sr = s0 & 2047;
            const int kb = sr >> 6;
            const int kslice = mi;               // (mi*16+g*4)>>4
            const int khalf = (g >> 1) & 1;
            const int e0 = (g & 1) * 4;
#pragma unroll
            for (int ni = 0; ni < 4; ++ni) {
                const int n = n0 + wn + ni * 16 + c;
                const int h_ = n >> 6;
                const int nei = ni >> 1;
                const int l31 = (ni & 1) * 16 + c;
                const size_t base =
                    ((((size_t)(b_ * 16 + h_) * 32 + kb) * 4 + kslice) * 2 + nei) * 512
                    + (size_t)(khalf * 32 + l31) * 8 + e0;
                ushort4 pk;
                pk.x = f2bf(acc[mi][ni][0] + bv[ni]);
                pk.y = f2bf(acc[mi][ni][1] + bv[ni]);
                pk.z = f2bf(acc[mi][ni][2] + bv[ni]);
                pk.w = f2bf(acc[mi][ni][3] + bv[ni]);
                *(ushort4*)(Vsh + base) = pk;
            }
        }
    }
}

// ---------- GEMM 64x128 tile, fp32 out: final projection ----------
__global__ __launch_bounds__(256, 4)
void gemm64(const unsigned short* __restrict__ A,
            const unsigned short* __restrict__ W,
            const float* __restrict__ bias, float* __restrict__ out)
{
    __shared__ unsigned short As[4096];   // [64][64]  8KB
    __shared__ unsigned short Ws[8192];   // [128][64] 16KB

    const int t = threadIdx.x;
    const int lane = t & 63;
    const int g = lane >> 4;
    const int c = lane & 15;
    const int w = t >> 6;
    const int wm = (w >> 1) * 32;
    const int wn = (w & 1) * 64;
    const int m0 = blockIdx.y * 64;
    const int n0 = blockIdx.x * 128;

    const int srow = lane >> 3;
    const int scol = (lane & 7) * 8;

    const f32x4 zz = {0.f, 0.f, 0.f, 0.f};
    f32x4 acc[2][4];
#pragma unroll
    for (int mi = 0; mi < 2; ++mi)
#pragma unroll
        for (int ni = 0; ni < 4; ++ni) acc[mi][ni] = zz;

    for (int kt = 0; kt < 16; ++kt) {
        const int k0 = kt * 64;
        gl16(A + (size_t)(m0 + 16 * w + srow) * 1024 + k0 + scol,
             (unsigned short*)As + (2 * w) * 512);
        gl16(A + (size_t)(m0 + 16 * w + 8 + srow) * 1024 + k0 + scol,
             (unsigned short*)As + (2 * w + 1) * 512);
#pragma unroll
        for (int r = 0; r < 4; ++r)
            gl16(W + (size_t)(n0 + 32 * w + 8 * r + srow) * 1024 + k0 + scol,
                 (unsigned short*)Ws + (w * 4 + r) * 512);
        __syncthreads();
#pragma unroll
        for (int kk = 0; kk < 2; ++kk) {
            fragAB af[2], bfr[4];
#pragma unroll
            for (int mi = 0; mi < 2; ++mi)
                af[mi] = *(const fragAB*)((char*)As + (wm + mi * 16 + c) * 128 + kk * 64 + g * 16);
#pragma unroll
            for (int ni = 0; ni < 4; ++ni)
                bfr[ni] = *(const fragAB*)((char*)Ws + (wn + ni * 16 + c) * 128 + kk * 64 + g * 16);
#pragma unroll
            for (int mi = 0; mi < 2; ++mi)
#pragma unroll
                for (int ni = 0; ni < 4; ++ni)
                    acc[mi][ni] = MFMA16(af[mi], bfr[ni], acc[mi][ni]);
        }
        __syncthreads();
    }

#pragma unroll
    for (int ni = 0; ni < 4; ++ni) {
        const float bv = bias[n0 + wn + ni * 16 + c];
#pragma unroll
        for (int mi = 0; mi < 2; ++mi)
#pragma unroll
            for (int j = 0; j < 4; ++j) {
                const int grow = m0 + wm + mi * 16 + g * 4 + j;
                const int gcol = n0 + wn + ni * 16 + c;
                out[(size_t)grow * 1024 + gcol] = acc[mi][ni][j] + bv;
            }
    }
}

// ---------- fused sine attention v4b: 8 waves (4 q-quarters x 2 k-halves) ----------
// QBLK=128, KVBLK=64, 512 threads, grid 512 (2 blocks/CU -> 4 waves/SIMD).
// R6 numerics exactly (Q unscaled, st*SIN_SC in f32); only decomposition changed.
__global__ __launch_bounds__(512, 4)
void attn_kernel(const unsigned short* __restrict__ Qg,
                 const unsigned short* __restrict__ Ksh,
                 const unsigned short* __restrict__ Vsh,
                 unsigned short* __restrict__ AO)
{
    __shared__ char smem[32768];
    unsigned short* const KldsU = (unsigned short*)smem;            // 2 bufs x 8KB
    unsigned short* const VldsU = (unsigned short*)(smem + 16384);  // 2 bufs x 8KB
    float* const red = (float*)smem;                                // 32KB reduce (aliased)

    const int t = threadIdx.x;
    const int lane = t & 63;
    const int l31 = lane & 31;
    const int lh = lane >> 5;
    const int w = t >> 6;
    const int qh = w >> 1;     // q-quarter owned (32 rows)
    const int kbl = w & 1;     // k-half owned

    // XCD-chunked bijective swizzle (512 blocks, 64 per XCD)
    const int bid = blockIdx.x;
    const int lb = (bid & 7) * 64 + (bid >> 3);
    const int qb = lb & 15;
    const int h = (lb >> 4) & 15;
    const int b = lb >> 8;
    const int qbase = qb * 128;

    const unsigned short* Kc = Ksh + (size_t)(b * 16 + h) * 131072;
    const unsigned short* Vc = Vsh + (size_t)(b * 16 + h) * 131072;

    // Q fragments (loop-invariant): lane holds Q[qbase+qh*32+l31][ds*16+lh*8..+8]
    fragAB qf[4];
#pragma unroll
    for (int ds = 0; ds < 4; ++ds)
        qf[ds] = *(const fragAB*)(Qg
            + (size_t)(b * 2048 + qbase + qh * 32 + l31) * 1024
            + h * 64 + ds * 16 + lh * 8);

    f32x16 o[2];
#pragma unroll
    for (int ni = 0; ni < 2; ++ni)
#pragma unroll
        for (int r = 0; r < 16; ++r) o[ni][r] = 0.f;

    // prologue: stage kb=0 into buf 0 (each wave: 1 K-blk + 1 V-blk of 1KB)
    gl16(Kc + w * 512 + lane * 8, KldsU + w * 512);
    gl16(Vc + w * 512 + lane * 8, VldsU + w * 512);
    __syncthreads();

    for (int kb = 0; kb < 32; ++kb) {
        const int buf = kb & 1;

        if (kb < 31) {   // prefetch kb+1 into buf^1 (drained by bottom syncthreads)
            const int nb = buf ^ 1;
            const size_t so = (size_t)(kb + 1) * 4096;
            gl16(Kc + so + w * 512 + lane * 8, KldsU + nb * 4096 + w * 512);
            gl16(Vc + so + w * 512 + lane * 8, VldsU + nb * 4096 + w * 512);
        }

        // conflict-free frag reads (lane*16B each)
        fragAB kf[4];
#pragma unroll
        for (int ds = 0; ds < 4; ++ds)
            kf[ds] = *(const fragAB*)(KldsU + buf * 4096 + (kbl * 4 + ds) * 512 + lane * 8);
        fragAB vf[2][2];
#pragma unroll
        for (int ks = 0; ks < 2; ++ks)
#pragma unroll
            for (int ni = 0; ni < 2; ++ni)
                vf[ks][ni] = *(const fragAB*)(VldsU + buf * 4096
                                              + ((kbl * 2 + ks) * 2 + ni) * 512 + lane * 8);

        // QK: St = K(own 32k) . Q(own 32q)^T over d=64
        f32x16 st;
#pragma unroll
        for (int r = 0; r < 16; ++r) st[r] = 0.f;
        __builtin_amdgcn_s_setprio(1);
#pragma unroll
        for (int ds = 0; ds < 4; ++ds)
            st = MFMA32(kf[ds], qf[ds], st);
        __builtin_amdgcn_s_setprio(0);

        // sin(SIN_SC * st) -> bf16 pairs -> permlane32_swap -> PV A-frags
        unsigned int u[8];
#pragma unroll
        for (int i = 0; i < 8; ++i)
            u[i] = cvtpk(fsin_rev(st[2 * i] * SIN_SC), fsin_rev(st[2 * i + 1] * SIN_SC));
        swap32(u[0], u[2]); swap32(u[1], u[3]);
        swap32(u[4], u[6]); swap32(u[5], u[7]);
        union { u32x4 u; fragAB f; } pa0, pa1;
        pa0.u = (u32x4){u[0], u[1], u[2], u[3]};
        pa1.u = (u32x4){u[4], u[5], u[6], u[7]};

        __builtin_amdgcn_s_setprio(1);
#pragma unroll
        for (int ni = 0; ni < 2; ++ni) {
            o[ni] = MFMA32(pa0.f, vf[0][ni], o[ni]);
            o[ni] = MFMA32(pa1.f, vf[1][ni], o[ni]);
        }
        __builtin_amdgcn_s_setprio(0);

        __syncthreads();   // next buf staged; this buf's readers done
    }

    // cross-k-half reduce: kbl=1 waves write partial O, kbl=0 waves add + store
    if (kbl) {
#pragma unroll
        for (int ni = 0; ni < 2; ++ni)
#pragma unroll
            for (int r = 0; r < 16; ++r)
                red[((qh * 2 + ni) * 16 + r) * 64 + lane] = o[ni][r];
    }
    __syncthreads();
    if (!kbl) {
#pragma unroll
        for (int ni = 0; ni < 2; ++ni)
#pragma unroll
            for (int r = 0; r < 16; ++r) {
                const float v = o[ni][r]
                    + red[((qh * 2 + ni) * 16 + r) * 64 + lane];
                const int q = qbase + qh * 32 + (r & 3) + 8 * (r >> 2) + 4 * lh;
                AO[(size_t)(b * 2048 + q) * 1024 + h * 64 + ni * 32 + l31] = f2bf(v);
            }
    }
}

// ---------- launcher ----------
extern "C" void kernel_launch(void* const* d_in, const int* in_sizes, int n_in,
                              void* d_out, int out_size, void* d_ws, size_t ws_size,
                              hipStream_t stream) {
    (void)in_sizes; (void)n_in; (void)out_size; (void)ws_size;
    const float* x  = (const float*)d_in[0];
    const float* Wq = (const float*)d_in[1];
    const float* bq = (const float*)d_in[2];
    const float* Wk = (const float*)d_in[3];
    const float* bk = (const float*)d_in[4];
    const float* Wv = (const float*)d_in[5];
    const float* bv = (const float*)d_in[6];
    const float* Wo = (const float*)d_in[7];
    const float* bo = (const float*)d_in[8];

    char* ws = (char*)d_ws;
    unsigned short* xb    = (unsigned short*)(ws);                    // 8MB
    unsigned short* Wqb   = (unsigned short*)(ws + (8u  << 20));      // 2MB each
    unsigned short* Wkb   = (unsigned short*)(ws + (10u << 20));
    unsigned short* Wvb   = (unsigned short*)(ws + (12u << 20));
    unsigned short* Wob   = (unsigned short*)(ws + (14u << 20));
    unsigned short* Qb    = (unsigned short*)(ws + (16u << 20));      // 8MB row-major
    unsigned short* Kshuf = (unsigned short*)(ws + (24u << 20));      // 8MB frag-order
    unsigned short* Vshuf = (unsigned short*)(ws + (32u << 20));      // 8MB frag-order
    unsigned short* AO    = (unsigned short*)(ws + (40u << 20));      // 8MB row-major

    cvt_all<<<8192, 256, 0, stream>>>(x, Wq, Wk, Wv, Wo, xb, Wqb, Wkb, Wvb, Wob);

    gemm_k<<<dim3(8, 32, 3), 256, 0, stream>>>(xb, Wqb, Wkb, Wvb, bq, bk, bv,
                                               Qb, Kshuf, Vshuf);

    attn_kernel<<<512, 512, 0, stream>>>(Qb, Kshuf, Vshuf, AO);

    gemm64<<<dim3(8, 64), 256, 0, stream>>>(AO, Wob, bo, (float*)d_out);
}